// Round 2
// baseline (436.397 us; speedup 1.0000x reference)
//
#include <hip/hip_runtime.h>

// Round 1: split fill into (a) branchless pure zero-fill at memset speed and
// (b) diagonal writes folded into the scatter kernel.
//   R0 post-mortem: fused diag logic (dynamic array index) made the 256MB fill
//   run at ~1.8 TB/s vs rocclr memset's 4.8 TB/s on the same machine.

typedef float f4 __attribute__((ext_vector_type(4)));

__global__ __launch_bounds__(256) void zero_fill_kernel(
    f4* __restrict__ out, long long n4)
{
    long long t = (long long)blockIdx.x * blockDim.x + threadIdx.x;
    if (t < n4) {
        f4 z = {0.f, 0.f, 0.f, 0.f};
        __builtin_nontemporal_store(z, &out[t]);
    }
}

__global__ __launch_bounds__(256) void scatter_kernel(
    float* __restrict__ out,
    const int* __restrict__ idx,          // [2, M] int32: row 0 = i, row 1 = j
    const float* __restrict__ vals,       // [M]
    const float* __restrict__ h_local,    // [D]
    float scale,
    int m,
    int d,
    int logd)
{
    int k = blockIdx.x * blockDim.x + threadIdx.x;
    if (k >= m) return;
    int i = idx[k];
    int j = idx[m + k];
    float v = vals[k] * scale;
    out[((long long)i << logd) + j] = v;
    out[((long long)j << logd) + i] = v;
    // Diagonal: only first d threads (d=8192 << m). No scale on h_local.
    if (k < d) {
        out[((long long)k << logd) + k] = h_local[k];
    }
}

extern "C" void kernel_launch(void* const* d_in, const int* in_sizes, int n_in,
                              void* d_out, int out_size, void* d_ws, size_t ws_size,
                              hipStream_t stream) {
    const float* h_local = (const float*)d_in[0];
    const float* V_int   = (const float*)d_in[1];
    const int*   idx     = (const int*)d_in[2];

    const int d = in_sizes[0];            // 8192
    const int m = in_sizes[1];            // 1,600,000

    int logd = 0;
    while ((1 << logd) < d) ++logd;

    const double iscale_d = 1.0 - 0.2 / sqrt(log((double)d));
    const float  iscale   = (float)iscale_d;

    float* out = (float*)d_out;

    // Kernel 1: pure zero fill, D*D/4 float4 chunks (branchless, nt stores).
    const long long n4 = ((long long)d * d) >> 2;
    const int block = 256;
    const long long grid_fill = (n4 + block - 1) / block;
    zero_fill_kernel<<<(dim3)(unsigned)grid_fill, block, 0, stream>>>((f4*)out, n4);

    // Kernel 2: symmetric scatter + diagonal (stream-ordered after the fill).
    const int grid_sc = (m + block - 1) / block;
    scatter_kernel<<<grid_sc, block, 0, stream>>>(out, idx, V_int, h_local,
                                                  iscale, m, d, logd);
}

// Round 3
// 364.189 us; speedup vs baseline: 1.1983x; 1.1983x over previous
//
#include <hip/hip_runtime.h>

// Round 2: revert NT stores -> plain cached float4 stores.
//   R1 post-mortem: nontemporal fill bypassed L2/L3, so the scatter's 3.2M
//   random 4B stores lost Infinity-Cache warmth (matrix = 256MB = L3 size)
//   and went to cold HBM lines: total 363 -> 436 us. Cached fill keeps the
//   whole matrix L3-resident for the scatter.

typedef float f4 __attribute__((ext_vector_type(4)));

__global__ __launch_bounds__(256) void zero_fill_kernel(
    f4* __restrict__ out, long long n4)
{
    long long t = (long long)blockIdx.x * blockDim.x + threadIdx.x;
    if (t < n4) {
        f4 z = {0.f, 0.f, 0.f, 0.f};
        out[t] = z;
    }
}

__global__ __launch_bounds__(256) void scatter_kernel(
    float* __restrict__ out,
    const int* __restrict__ idx,          // [2, M] int32: row 0 = i, row 1 = j
    const float* __restrict__ vals,       // [M]
    const float* __restrict__ h_local,    // [D]
    float scale,
    int m,
    int d,
    int logd)
{
    int k = blockIdx.x * blockDim.x + threadIdx.x;
    if (k >= m) return;
    int i = idx[k];
    int j = idx[m + k];
    float v = vals[k] * scale;
    out[((long long)i << logd) + j] = v;
    out[((long long)j << logd) + i] = v;
    // Diagonal: only first d threads (d=8192 << m). No scale on h_local.
    if (k < d) {
        out[((long long)k << logd) + k] = h_local[k];
    }
}

extern "C" void kernel_launch(void* const* d_in, const int* in_sizes, int n_in,
                              void* d_out, int out_size, void* d_ws, size_t ws_size,
                              hipStream_t stream) {
    const float* h_local = (const float*)d_in[0];
    const float* V_int   = (const float*)d_in[1];
    const int*   idx     = (const int*)d_in[2];

    const int d = in_sizes[0];            // 8192
    const int m = in_sizes[1];            // 1,600,000

    int logd = 0;
    while ((1 << logd) < d) ++logd;

    const double iscale_d = 1.0 - 0.2 / sqrt(log((double)d));
    const float  iscale   = (float)iscale_d;

    float* out = (float*)d_out;

    // Kernel 1: pure zero fill, D*D/4 float4 chunks (branchless, cached).
    const long long n4 = ((long long)d * d) >> 2;
    const int block = 256;
    const long long grid_fill = (n4 + block - 1) / block;
    zero_fill_kernel<<<(dim3)(unsigned)grid_fill, block, 0, stream>>>((f4*)out, n4);

    // Kernel 2: symmetric scatter + diagonal (stream-ordered after the fill).
    const int grid_sc = (m + block - 1) / block;
    scatter_kernel<<<grid_sc, block, 0, stream>>>(out, idx, V_int, h_local,
                                                  iscale, m, d, logd);
}